// Round 6
// baseline (22.883 us; speedup 1.0000x reference)
//
#include <hip/hip_runtime.h>

#define NBATCH 4
#define NPTS   4096
#define XPT    8                 // x-points per thread
#define XCHUNK (256 * XPT)       // 2048
#define NXC    (NPTS / XCHUNK)   // 2
#define YCHUNK 128
#define NYC    (NPTS / YCHUNK)   // 32
#define BIGF   1e30f

// Fused both-direction chamfer partial-min kernel.
// grid = (NXC, NYC, 2*NBATCH) = (2, 32, 8) = 512 blocks; block = 256.
// dir 0: X=preds, Y=gts (mask folded into ry as +BIGF penalty)
// dir 1: X=gts,   Y=preds (mask applied at reduce)
// partial[((dir*NBATCH + b)*NYC + yc)*NPTS + x] = rx + min_{j in chunk}(ry_j - 2 x.y_j)
// 8 x-points per thread so each broadcast ds_read_b128 of a y-record feeds 8
// pairs -> LDS pipe pressure 1/8 instr/pair; inner loop is VALU-bound.
__global__ __launch_bounds__(256)
void chamfer_min_kernel(const float* __restrict__ preds,
                        const float* __restrict__ gts,
                        const int* __restrict__ mask,
                        float* __restrict__ partial,
                        float* __restrict__ out) {
    const int zc  = blockIdx.z;
    const int dir = zc >> 2;
    const int b   = zc & 3;
    const int tid = threadIdx.x;

    // zero the output scalar exactly once; the reduce kernel (next dispatch,
    // same stream) accumulates only after this kernel fully completes.
    if ((zc | blockIdx.x | blockIdx.y | tid) == 0) out[0] = 0.0f;

    const float* X = (dir == 0 ? preds : gts) + (size_t)b * NPTS * 3;
    const float* Y = (dir == 0 ? gts : preds) + (size_t)b * NPTS * 3;

    __shared__ float4 sy[YCHUNK];
    const int cbase = blockIdx.y * YCHUNK;
    if (tid < YCHUNK) {
        const int j = cbase + tid;
        const float y0 = Y[j * 3 + 0];
        const float y1 = Y[j * 3 + 1];
        const float y2 = Y[j * 3 + 2];
        float ry = y0 * y0 + y1 * y1 + y2 * y2;
        if (dir == 0 && mask[b * NPTS + j] == 0) ry = BIGF;
        sy[tid] = make_float4(y0, y1, y2, ry);
    }
    __syncthreads();

    // load 8 x-points; pre-scale by -2 so inner loop is pure fma vs ry
    float a0[XPT], a1[XPT], a2[XPT], rx[XPT], m[XPT];
    const int xbase = blockIdx.x * XCHUNK + tid;
    #pragma unroll
    for (int i = 0; i < XPT; ++i) {
        const int x = xbase + i * 256;
        float v0 = X[x * 3 + 0], v1 = X[x * 3 + 1], v2 = X[x * 3 + 2];
        rx[i] = v0 * v0 + v1 * v1 + v2 * v2;
        a0[i] = -2.0f * v0; a1[i] = -2.0f * v1; a2[i] = -2.0f * v2;
        m[i] = BIGF;
    }

    #pragma unroll 2
    for (int k = 0; k < YCHUNK; k += 4) {
        const float4 p0 = sy[k + 0];
        const float4 p1 = sy[k + 1];
        const float4 p2 = sy[k + 2];
        const float4 p3 = sy[k + 3];
        #pragma unroll
        for (int i = 0; i < XPT; ++i) {
            const float t0 = fmaf(a0[i], p0.x, fmaf(a1[i], p0.y, fmaf(a2[i], p0.z, p0.w)));
            const float t1 = fmaf(a0[i], p1.x, fmaf(a1[i], p1.y, fmaf(a2[i], p1.z, p1.w)));
            const float t2 = fmaf(a0[i], p2.x, fmaf(a1[i], p2.y, fmaf(a2[i], p2.z, p2.w)));
            const float t3 = fmaf(a0[i], p3.x, fmaf(a1[i], p3.y, fmaf(a2[i], p3.z, p3.w)));
            m[i] = fminf(fminf(m[i], t0), t1);   // -> v_min3_f32
            m[i] = fminf(fminf(m[i], t2), t3);   // -> v_min3_f32
        }
    }

    float* prow = partial + ((size_t)(dir * NBATCH + b) * NYC + blockIdx.y) * NPTS
                + blockIdx.x * XCHUNK + tid;
    #pragma unroll
    for (int i = 0; i < XPT; ++i)
        prow[i * 256] = rx[i] + m[i];
}

// Final reduce: per point, min over the NYC=32 chunk-partials (2 threads/point,
// 16 each, shfl_xor combine), mask dir-1 (gt side), sum into out[0].
// grid = 2*(2*NBATCH*NPTS)/256 = 256 blocks; block = 256.
__global__ __launch_bounds__(256)
void chamfer_reduce_kernel(const float* __restrict__ partial,
                           const int* __restrict__ mask,
                           float* __restrict__ out) {
    const int gid = blockIdx.x * blockDim.x + threadIdx.x;
    const int h   = gid & 1;            // which half of the 32 chunks
    const int p   = gid >> 1;           // point id in [0, 2*NBATCH*NPTS)
    const int dir = p >> 14;
    const int b   = (p >> 12) & 3;
    const int x   = p & 4095;

    const float* base = partial + ((size_t)(dir * NBATCH + b) * NYC) * NPTS + x
                      + (size_t)(h * 16) * NPTS;
    float m = base[0];
    #pragma unroll
    for (int c = 1; c < 16; ++c) m = fminf(m, base[(size_t)c * NPTS]);

    // combine the two halves (lanes 2i, 2i+1)
    m = fminf(m, __shfl_xor(m, 1, 64));

    float v = 0.0f;
    if (h == 0) {
        v = m;
        if (dir == 1 && mask[b * NPTS + x] == 0) v = 0.0f;
    }

    // wave64 shuffle reduce
    #pragma unroll
    for (int off = 32; off > 0; off >>= 1)
        v += __shfl_down(v, off, 64);

    __shared__ float wsum[4];
    const int wave = threadIdx.x >> 6;
    if ((threadIdx.x & 63) == 0) wsum[wave] = v;
    __syncthreads();
    if (threadIdx.x == 0)
        atomicAdd(out, wsum[0] + wsum[1] + wsum[2] + wsum[3]);
}

extern "C" void kernel_launch(void* const* d_in, const int* in_sizes, int n_in,
                              void* d_out, int out_size, void* d_ws, size_t ws_size,
                              hipStream_t stream) {
    const float* preds = (const float*)d_in[0];  // [B, Npred, 3]
    const float* gts   = (const float*)d_in[1];  // [B, Ngt, 3]
    const int*   mask  = (const int*)d_in[2];    // [B, Ngt]
    float* out = (float*)d_out;

    float* partial = (float*)d_ws;  // [2][NBATCH][NYC][NPTS] = 4 MB

    dim3 grid(NXC, NYC, 2 * NBATCH);
    chamfer_min_kernel<<<grid, 256, 0, stream>>>(preds, gts, mask, partial, out);

    chamfer_reduce_kernel<<<2 * (2 * NBATCH * NPTS) / 256, 256, 0, stream>>>(
        partial, mask, out);
}